// Round 3
// baseline (960.415 us; speedup 1.0000x reference)
//
#include <hip/hip_runtime.h>

typedef __attribute__((ext_vector_type(8))) short short8;
typedef __attribute__((ext_vector_type(4))) float f32x4;

__device__ __forceinline__ float bf2f(unsigned short u) {
    union { unsigned int i; float f; } v; v.i = ((unsigned int)u) << 16; return v.f;
}
__device__ __forceinline__ unsigned short f2bf(float f) {
    union { float f; unsigned int i; } v; v.f = f;
    unsigned int i = v.i;
    return (unsigned short)((i + 0x7FFFu + ((i >> 16) & 1u)) >> 16);  // RNE
}
// load one external float (buffer may be f32 or bf16 per flag)
__device__ __forceinline__ float ldext(const void* p, size_t i, int xf) {
    return xf ? ((const float*)p)[i] : bf2f(((const unsigned short*)p)[i]);
}
__device__ __forceinline__ float scrub(float v) {
    // NaN/inf -> sentinel 9.0 (diagnostic: absmax~9 means arithmetic NaN)
    return (__builtin_fabsf(v) < 1e30f) ? v : 9.0f;
}

// ---------------- dtype probes ----------------
// flags[0]: 1 => edge_index stored as int64 words; flags[1]: 1 => floats are f32
__global__ void k_detect(const int* __restrict__ ei, const unsigned short* __restrict__ xs,
                         int* __restrict__ flags) {
    if (blockIdx.x == 0 && threadIdx.x == 0) {
        int orv = 0;
        for (int i = 1; i < 256; i += 2) orv |= ei[i];
        flags[0] = (orv == 0) ? 1 : 0;
        int cnt = 0;
        for (int i = 0; i < 256; ++i) {
            int e = (xs[i] >> 7) & 0xFF;            // bf16 exponent field
            cnt += (e >= 97 && e <= 159) ? 1 : 0;   // |v| in [2^-30, 2^32]
        }
        flags[1] = (cnt >= 240) ? 0 : 1;  // all-plausible => genuine bf16
    }
}

// ---------------- CSR build ----------------

__global__ void k_zero(int* __restrict__ p, int n) {
    int i = blockIdx.x * 256 + threadIdx.x;
    if (i < n) p[i] = 0;
}

__global__ void k_count(const int* __restrict__ ei, const int* __restrict__ flags,
                        int* __restrict__ cnt, int e, int n) {
    int i = blockIdx.x * 256 + threadIdx.x;
    if (i < e) {
        int f = flags[0];
        int c = ei[((long)(e + i)) << f];   // col = target
        if ((unsigned)c >= (unsigned)n) c = 0;
        atomicAdd(&cnt[c], 1);
    }
}

__global__ __launch_bounds__(1024) void k_scan(
    int* __restrict__ cnt, int* __restrict__ rowptr,
    float* __restrict__ dinv, int n) {
    __shared__ int wsum[16];
    __shared__ int carry_s;
    int t = threadIdx.x, lane = t & 63, wv = t >> 6;
    if (t == 0) carry_s = 0;
    __syncthreads();
    for (int base = 0; base < n; base += 1024) {
        int i = base + t;
        int v = (i < n) ? cnt[i] : 0;
        if (i < n) dinv[i] = rsqrtf((float)(v + 1));  // +1 self loop
        int s = v;
        for (int off = 1; off < 64; off <<= 1) {
            int x = __shfl_up(s, off);
            if (lane >= off) s += x;
        }
        if (lane == 63) wsum[wv] = s;
        __syncthreads();
        if (wv == 0 && lane < 16) {
            int w = wsum[lane];
            for (int off = 1; off < 16; off <<= 1) {
                int x = __shfl_up(w, off);
                if (lane >= off) w += x;
            }
            wsum[lane] = w;
        }
        __syncthreads();
        int wbase = (wv == 0) ? 0 : wsum[wv - 1];
        int carry = carry_s;
        int incl = carry + wbase + s;
        if (i < n) { int ex = incl - v; rowptr[i] = ex; cnt[i] = ex; }  // cnt -> cursor
        __syncthreads();
        if (t == 1023) carry_s = incl;
        __syncthreads();
    }
    if (t == 0) rowptr[n] = carry_s;
}

__global__ void k_scatter(const int* __restrict__ ei, const int* __restrict__ flags,
                          int* __restrict__ cursor, int* __restrict__ csr_src,
                          int e, int n) {
    int i = blockIdx.x * 256 + threadIdx.x;
    if (i < e) {
        int f = flags[0];
        int c = ei[((long)(e + i)) << f];
        int r = ei[((long)i) << f];
        if ((unsigned)c >= (unsigned)n) c = 0;
        if ((unsigned)r >= (unsigned)n) r = 0;
        int p = atomicAdd(&cursor[c], 1);
        if ((unsigned)p < (unsigned)e) csr_src[p] = r;
    }
}

// ---------------- MFMA GEMM: C[M,128] = A[M,K] @ W[K,128] (+bias) ----------------
// 16x16x32 bf16 MFMA. A frag: m=lane&15, k=quad*8+j. B frag: n=lane&15, k=quad*8+j.
// C/D: col=lane&15, row=quad*4+reg. W transposed into LDS (Kpad=136).
// a_ext/c_ext: that buffer uses the external float format (f32 when flags[1]).

#define KPAD 136

__device__ __forceinline__ short8 load_frag(const void* A, size_t row, int K, int off, int f32m) {
    if (!f32m)
        return *(const short8*)((const unsigned short*)A + row * (size_t)K + off);
    const float* p = (const float*)A + row * (size_t)K + off;
    short8 r;
#pragma unroll
    for (int j = 0; j < 8; ++j) r[j] = (short)f2bf(p[j]);
    return r;
}

__global__ __launch_bounds__(256) void k_gemm(
    const void* __restrict__ A, const void* __restrict__ W,
    void* __restrict__ Cbase, const void* __restrict__ bias,
    int M, int K, const int* __restrict__ flags,
    int a_ext, int c_half, int c_ext) {
    __shared__ unsigned short lds[128 * KPAD];
    int xf = flags[1];
    int af = a_ext & xf;
    int cf = c_ext & xf;
    // half offset inside d_out uses the FINAL out element size (xf ? 4 : 2)
    char* cp = (char*)Cbase + (size_t)c_half * (size_t)M * 128 * (xf ? 4 : 2);

    int tid = threadIdx.x;
    int wave = tid >> 6, lane = tid & 63;
    int quad = lane >> 4, l16 = lane & 15;
    int row0 = blockIdx.x * 128 + wave * 32;

    f32x4 acc[2][8];
    for (int m = 0; m < 2; ++m)
        for (int t = 0; t < 8; ++t)
            acc[m][t] = (f32x4){0.f, 0.f, 0.f, 0.f};

    size_t ar0 = (size_t)min(row0 + l16, M - 1);
    size_t ar1 = (size_t)min(row0 + 16 + l16, M - 1);

    for (int kc = 0; kc < K; kc += 128) {
        __syncthreads();
        if (xf) {
            for (int i = tid; i < 128 * 128; i += 256) {
                int k = i >> 7, n = i & 127;
                lds[n * KPAD + k] = f2bf(((const float*)W)[(size_t)(kc + k) * 128 + n]);
            }
        } else {
            for (int i = tid; i < 128 * 128; i += 256) {
                int k = i >> 7, n = i & 127;
                lds[n * KPAD + k] = ((const unsigned short*)W)[(size_t)(kc + k) * 128 + n];
            }
        }
        __syncthreads();
        for (int ks = 0; ks < 128; ks += 32) {
            short8 a0 = load_frag(A, ar0, K, kc + ks + quad * 8, af);
            short8 a1 = load_frag(A, ar1, K, kc + ks + quad * 8, af);
            for (int t = 0; t < 8; ++t) {
                short8 bf = *(const short8*)(&lds[(t * 16 + l16) * KPAD + ks + quad * 8]);
                acc[0][t] = __builtin_amdgcn_mfma_f32_16x16x32_bf16(a0, bf, acc[0][t], 0, 0, 0);
                acc[1][t] = __builtin_amdgcn_mfma_f32_16x16x32_bf16(a1, bf, acc[1][t], 0, 0, 0);
            }
        }
    }
    for (int t = 0; t < 8; ++t) {
        int colx = t * 16 + l16;
        float bv = bias ? ldext(bias, colx, xf) : 0.f;
        for (int m = 0; m < 2; ++m) {
            for (int r = 0; r < 4; ++r) {
                int row = row0 + m * 16 + quad * 4 + r;
                if (row < M) {
                    float v = scrub(acc[m][t][r] + bv);
                    if (cf) ((float*)cp)[(size_t)row * 128 + colx] = v;
                    else ((unsigned short*)cp)[(size_t)row * 128 + colx] = f2bf(v);
                }
            }
        }
    }
}

// ---------------- aggregation ----------------
// z[v] = sum_{u in N(v) U {v}} h[u]*dinv[u]*dinv[v] + b ; h is always internal bf16.

__global__ __launch_bounds__(256) void k_agg(
    const void* __restrict__ hbase, int h_half,
    const int* __restrict__ rowptr, const int* __restrict__ csr_src,
    const float* __restrict__ dinv, const void* __restrict__ bias,
    void* __restrict__ z, int z_ext,
    int n, int etot, const int* __restrict__ flags) {
    int wid = (blockIdx.x * 256 + threadIdx.x) >> 6;
    if (wid >= n) return;
    int xf = flags[1];
    int zf = z_ext & xf;
    const unsigned short* h = (const unsigned short*)
        ((const char*)hbase + (size_t)h_half * (size_t)n * 128 * (xf ? 4 : 2));
    int lane = threadIdx.x & 63;
    float di = dinv[wid];
    int s = rowptr[wid], e = rowptr[wid + 1];
    if (e > etot) e = etot;
    if (s < 0) s = 0;

    ushort2 hv = *(const ushort2*)(h + (size_t)wid * 128 + lane * 2);
    float sw = di * di;
    float a0 = bf2f(hv.x) * sw;
    float a1 = bf2f(hv.y) * sw;

    for (int i = s; i < e; ++i) {
        int u = csr_src[i];
        if ((unsigned)u >= (unsigned)n) u = 0;
        float w = di * dinv[u];
        ushort2 hu = *(const ushort2*)(h + (size_t)u * 128 + lane * 2);
        a0 += bf2f(hu.x) * w;
        a1 += bf2f(hu.y) * w;
    }
    a0 = scrub(a0 + ldext(bias, lane * 2, xf));
    a1 = scrub(a1 + ldext(bias, lane * 2 + 1, xf));
    if (zf) {
        float2 o; o.x = a0; o.y = a1;
        *(float2*)((float*)z + (size_t)wid * 128 + lane * 2) = o;
    } else {
        ushort2 o; o.x = f2bf(a0); o.y = f2bf(a1);
        *(ushort2*)((unsigned short*)z + (size_t)wid * 128 + lane * 2) = o;
    }
}

// ---------------- launch ----------------

static inline size_t alignup(size_t x) { return (x + 255) & ~(size_t)255; }

extern "C" void kernel_launch(void* const* d_in, const int* in_sizes, int n_in,
                              void* d_out, int out_size, void* d_ws, size_t ws_size,
                              hipStream_t stream) {
    const void* x  = d_in[0];
    const int*  ei = (const int*)d_in[1];
    const void* W1 = d_in[2];
    const void* b1 = d_in[3];
    const void* W2 = d_in[4];
    const void* b2 = d_in[5];
    const void* Wp = d_in[6];
    const void* bp = d_in[7];

    const int HID = in_sizes[3];            // 128
    const int IN_DIM = in_sizes[2] / HID;   // 256
    const int N = in_sizes[0] / IN_DIM;     // 100000
    const int E = in_sizes[1] / 2;          // 1600000

    // workspace layout
    char* w = (char*)d_ws;
    int* flags = (int*)w;      w += 256;
    int* cnt = (int*)w;        w += alignup(sizeof(int) * (size_t)N);     // -> cursor
    int* rowptr = (int*)w;     w += alignup(sizeof(int) * (size_t)(N + 1));
    float* dinv = (float*)w;   w += alignup(sizeof(float) * (size_t)N);
    int* csr_src = (int*)w;    w += alignup(sizeof(int) * (size_t)E);
    size_t fixed = (size_t)(w - (char*)d_ws);
    size_t bufbytes = alignup((size_t)N * HID * 2);
    bool wsmode = ws_size >= fixed + 2 * bufbytes;

    // h scratch and z1 scratch: in ws when possible, else inside d_out halves.
    void* hC;  int h_half;      // where GEMM1/2 write h (always bf16)
    void* z1p;                  // z1 scratch (always bf16, "half 0" position)
    if (wsmode) {
        hC = (void*)w;  h_half = 0;
        z1p = (void*)(w + bufbytes);
    } else {
        hC = d_out;     h_half = 1;   // byte offset computed on-device from out dtype
        z1p = d_out;                  // half 0
    }

    int nb256_N = (N + 255) / 256;
    int nb256_E = (E + 255) / 256;
    int gemm_blocks = (N + 127) / 128;
    int agg_blocks = (N + 3) / 4;

    // probes + CSR build
    k_detect<<<1, 64, 0, stream>>>(ei, (const unsigned short*)x, flags);
    k_zero<<<nb256_N, 256, 0, stream>>>(cnt, N);
    k_count<<<nb256_E, 256, 0, stream>>>(ei, flags, cnt, E, N);
    k_scan<<<1, 1024, 0, stream>>>(cnt, rowptr, dinv, N);
    k_scatter<<<nb256_E, 256, 0, stream>>>(ei, flags, cnt, csr_src, E, N);

    // layer 1: h1 = x@W1 (bf16 scratch); z1 = agg(h1)+b1 (bf16 scratch)
    k_gemm<<<gemm_blocks, 256, 0, stream>>>(x, W1, hC, nullptr, N, IN_DIM, flags,
                                            /*a_ext*/1, h_half, /*c_ext*/0);
    k_agg<<<agg_blocks, 256, 0, stream>>>(hC, h_half, rowptr, csr_src, dinv, b1,
                                          z1p, /*z_ext*/0, N, E, flags);

    // layer 2: h2 = z1@W2 (bf16 scratch); z2 = agg(h2)+b2 -> d_out half 0 (final fmt)
    k_gemm<<<gemm_blocks, 256, 0, stream>>>(z1p, W2, hC, nullptr, N, HID, flags,
                                            /*a_ext*/0, h_half, /*c_ext*/0);
    k_agg<<<agg_blocks, 256, 0, stream>>>(hC, h_half, rowptr, csr_src, dinv, b2,
                                          d_out, /*z_ext*/1, N, E, flags);

    // proj = z2@Wp + bp -> d_out half 1 (final fmt); A = z2 read back in final fmt
    k_gemm<<<gemm_blocks, 256, 0, stream>>>(d_out, Wp, d_out, bp, N, HID, flags,
                                            /*a_ext*/1, /*c_half*/1, /*c_ext*/1);
}

// Round 4
// 668.295 us; speedup vs baseline: 1.4371x; 1.4371x over previous
//
#include <hip/hip_runtime.h>

typedef __attribute__((ext_vector_type(8))) short short8;
typedef __attribute__((ext_vector_type(4))) float f32x4;

__device__ __forceinline__ float bf2f(unsigned short u) {
    union { unsigned int i; float f; } v; v.i = ((unsigned int)u) << 16; return v.f;
}
__device__ __forceinline__ unsigned short f2bf(float f) {
    union { float f; unsigned int i; } v; v.f = f;
    unsigned int i = v.i;
    return (unsigned short)((i + 0x7FFFu + ((i >> 16) & 1u)) >> 16);  // RNE
}
__device__ __forceinline__ float ldext(const void* p, size_t i, int xf) {
    return xf ? ((const float*)p)[i] : bf2f(((const unsigned short*)p)[i]);
}
__device__ __forceinline__ float scrub(float v) {
    return (__builtin_fabsf(v) < 1e30f) ? v : 9.0f;
}

// ---------------- dtype probes (one wave) ----------------
// flags[0]: 1 => edge_index is int64 words; flags[1]: 1 => floats are f32
__global__ void k_detect(const int* __restrict__ ei, const unsigned short* __restrict__ xs,
                         int* __restrict__ flags) {
    int lane = threadIdx.x;  // 64 threads, 1 block
    int orv = 0;
    for (int i = 2 * lane + 1; i < 256; i += 128) orv |= ei[i];
    int cnt = 0;
    for (int i = lane; i < 256; i += 64) {
        int e = (xs[i] >> 7) & 0xFF;
        cnt += (e >= 97 && e <= 159) ? 1 : 0;
    }
    for (int off = 32; off > 0; off >>= 1) {
        orv |= __shfl_down(orv, off);
        cnt += __shfl_down(cnt, off);
    }
    if (lane == 0) {
        flags[0] = (orv == 0) ? 1 : 0;
        flags[1] = (cnt >= 240) ? 0 : 1;
    }
}

// ---------------- CSR build ----------------

__global__ void k_zero(int* __restrict__ p, int n) {
    int i = blockIdx.x * 256 + threadIdx.x;
    if (i < n) p[i] = 0;
}

__global__ void k_count(const int* __restrict__ ei, const int* __restrict__ flags,
                        int* __restrict__ cnt, int e, int n) {
    int i = blockIdx.x * 256 + threadIdx.x;
    if (i < e) {
        int f = flags[0];
        int c = ei[((long)(e + i)) << f];
        if ((unsigned)c >= (unsigned)n) c = 0;
        atomicAdd(&cnt[c], 1);
    }
}

// parallel scan, CHUNK=2048 per 256-thread block
#define CHUNK 2048

__global__ __launch_bounds__(256) void k_part(const int* __restrict__ cnt,
                                              int* __restrict__ part, int n) {
    __shared__ int ws[4];
    int t = threadIdx.x, lane = t & 63, wv = t >> 6;
    int base = blockIdx.x * CHUNK + t * 8;
    int s = 0;
#pragma unroll
    for (int j = 0; j < 8; ++j) {
        int i = base + j;
        s += (i < n) ? cnt[i] : 0;
    }
    for (int off = 32; off > 0; off >>= 1) s += __shfl_down(s, off);
    if (lane == 0) ws[wv] = s;
    __syncthreads();
    if (t == 0) part[blockIdx.x] = ws[0] + ws[1] + ws[2] + ws[3];
}

// single block: exclusive scan of part[nb] in place; rowptr[n] = etot
__global__ __launch_bounds__(1024) void k_scanpart(int* __restrict__ part, int nb,
                                                   int* __restrict__ rowptr, int n, int etot) {
    __shared__ int ws[16];
    int t = threadIdx.x, lane = t & 63, wv = t >> 6;
    int v = (t < nb) ? part[t] : 0;
    int s = v;
    for (int off = 1; off < 64; off <<= 1) {
        int x = __shfl_up(s, off);
        if (lane >= off) s += x;
    }
    if (lane == 63) ws[wv] = s;
    __syncthreads();
    if (wv == 0 && lane < 16) {
        int w = ws[lane];
        for (int off = 1; off < 16; off <<= 1) {
            int x = __shfl_up(w, off);
            if (lane >= off) w += x;
        }
        ws[lane] = w;
    }
    __syncthreads();
    int excl = (wv ? ws[wv - 1] : 0) + s - v;
    __syncthreads();
    if (t < nb) part[t] = excl;
    if (t == 0) rowptr[n] = etot;
}

// each block scans its CHUNK locally + part[b]; writes rowptr, cursor(=cnt), dinv
__global__ __launch_bounds__(256) void k_apply(int* __restrict__ cnt,
                                               const int* __restrict__ part,
                                               int* __restrict__ rowptr,
                                               float* __restrict__ dinv, int n) {
    __shared__ int ws[4];
    int t = threadIdx.x, lane = t & 63, wv = t >> 6;
    int base = blockIdx.x * CHUNK + t * 8;
    int vals[8];
    int ls = 0;
#pragma unroll
    for (int j = 0; j < 8; ++j) {
        int i = base + j;
        vals[j] = (i < n) ? cnt[i] : 0;
        ls += vals[j];
    }
    int s = ls;
    for (int off = 1; off < 64; off <<= 1) {
        int x = __shfl_up(s, off);
        if (lane >= off) s += x;
    }
    if (lane == 63) ws[wv] = s;
    __syncthreads();
    int wbase = 0;
    for (int k = 0; k < 4; ++k) wbase += (k < wv) ? ws[k] : 0;
    int running = part[blockIdx.x] + wbase + (s - ls);
#pragma unroll
    for (int j = 0; j < 8; ++j) {
        int i = base + j;
        if (i < n) {
            rowptr[i] = running;
            cnt[i] = running;  // cursor
            dinv[i] = rsqrtf((float)(vals[j] + 1));
        }
        running += vals[j];
    }
}

__global__ void k_scatter(const int* __restrict__ ei, const int* __restrict__ flags,
                          int* __restrict__ cursor, int* __restrict__ csr_src,
                          int e, int n) {
    int i = blockIdx.x * 256 + threadIdx.x;
    if (i < e) {
        int f = flags[0];
        int c = ei[((long)(e + i)) << f];
        int r = ei[((long)i) << f];
        if ((unsigned)c >= (unsigned)n) c = 0;
        if ((unsigned)r >= (unsigned)n) r = 0;
        int p = atomicAdd(&cursor[c], 1);
        if ((unsigned)p < (unsigned)e) csr_src[p] = r;
    }
}

// ---------------- MFMA GEMM: C[M,128] = A[M,K] @ W[K,128] (+bias) ----------------

#define KPAD 136

__device__ __forceinline__ short8 load_frag(const void* A, size_t row, int K, int off, int f32m) {
    if (!f32m)
        return *(const short8*)((const unsigned short*)A + row * (size_t)K + off);
    const float* p = (const float*)A + row * (size_t)K + off;
    short8 r;
#pragma unroll
    for (int j = 0; j < 8; ++j) r[j] = (short)f2bf(p[j]);
    return r;
}

__global__ __launch_bounds__(256) void k_gemm(
    const void* __restrict__ A, const void* __restrict__ W,
    void* __restrict__ Cbase, const void* __restrict__ bias,
    int M, int K, const int* __restrict__ flags,
    int a_ext, int c_half, int c_ext) {
    __shared__ unsigned short lds[128 * KPAD];
    int xf = flags[1];
    int af = a_ext & xf;
    int cf = c_ext & xf;
    char* cp = (char*)Cbase + (size_t)c_half * (size_t)M * 128 * (xf ? 4 : 2);

    int tid = threadIdx.x;
    int wave = tid >> 6, lane = tid & 63;
    int quad = lane >> 4, l16 = lane & 15;
    int row0 = blockIdx.x * 128 + wave * 32;

    f32x4 acc[2][8];
    for (int m = 0; m < 2; ++m)
        for (int t = 0; t < 8; ++t)
            acc[m][t] = (f32x4){0.f, 0.f, 0.f, 0.f};

    size_t ar0 = (size_t)min(row0 + l16, M - 1);
    size_t ar1 = (size_t)min(row0 + 16 + l16, M - 1);

    for (int kc = 0; kc < K; kc += 128) {
        __syncthreads();
        if (xf) {
            for (int i = tid; i < 128 * 128; i += 256) {
                int k = i >> 7, n = i & 127;
                lds[n * KPAD + k] = f2bf(((const float*)W)[(size_t)(kc + k) * 128 + n]);
            }
        } else {
            for (int i = tid; i < 128 * 128; i += 256) {
                int k = i >> 7, n = i & 127;
                lds[n * KPAD + k] = ((const unsigned short*)W)[(size_t)(kc + k) * 128 + n];
            }
        }
        __syncthreads();
        for (int ks = 0; ks < 128; ks += 32) {
            short8 a0 = load_frag(A, ar0, K, kc + ks + quad * 8, af);
            short8 a1 = load_frag(A, ar1, K, kc + ks + quad * 8, af);
            for (int t = 0; t < 8; ++t) {
                short8 bf = *(const short8*)(&lds[(t * 16 + l16) * KPAD + ks + quad * 8]);
                acc[0][t] = __builtin_amdgcn_mfma_f32_16x16x32_bf16(a0, bf, acc[0][t], 0, 0, 0);
                acc[1][t] = __builtin_amdgcn_mfma_f32_16x16x32_bf16(a1, bf, acc[1][t], 0, 0, 0);
            }
        }
    }
    for (int t = 0; t < 8; ++t) {
        int colx = t * 16 + l16;
        float bv = bias ? ldext(bias, colx, xf) : 0.f;
        for (int m = 0; m < 2; ++m) {
            for (int r = 0; r < 4; ++r) {
                int row = row0 + m * 16 + quad * 4 + r;
                if (row < M) {
                    float v = scrub(acc[m][t][r] + bv);
                    if (cf) ((float*)cp)[(size_t)row * 128 + colx] = v;
                    else ((unsigned short*)cp)[(size_t)row * 128 + colx] = f2bf(v);
                }
            }
        }
    }
}

// ---------------- aggregation: 16-lane group per node, 8 features/lane ----------------
// z[v] = sum_{u in N(v) U {v}} h[u]*dinv[u]*dinv[v] + b ; h always internal bf16.
// 1-deep software pipeline on (u, dinv[u], h[u]).

__global__ __launch_bounds__(256) void k_agg(
    const void* __restrict__ hbase, int h_half,
    const int* __restrict__ rowptr, const int* __restrict__ csr_src,
    const float* __restrict__ dinv, const void* __restrict__ bias,
    void* __restrict__ z, int z_ext,
    int n, int etot, const int* __restrict__ flags) {
    int v = (blockIdx.x * 256 + threadIdx.x) >> 4;   // group id = node
    if (v >= n) return;
    int xf = flags[1];
    int zf = z_ext & xf;
    const unsigned short* h = (const unsigned short*)
        ((const char*)hbase + (size_t)h_half * (size_t)n * 128 * (xf ? 4 : 2));
    int g = threadIdx.x & 15;                         // lane-in-group, 8 feats
    float di = dinv[v];
    int s = rowptr[v], e = rowptr[v + 1];
    if (e > etot) e = etot;
    if (s < 0) s = 0;

    short8 hv = *(const short8*)(h + (size_t)v * 128 + g * 8);
    float sw = di * di;
    float acc[8];
#pragma unroll
    for (int j = 0; j < 8; ++j) acc[j] = bf2f((unsigned short)hv[j]) * sw;

    // pipelined neighbor loop
    int u0 = (s < e) ? csr_src[s] : 0;
    if ((unsigned)u0 >= (unsigned)n) u0 = 0;
    float du0 = dinv[u0];
    short8 h0 = *(const short8*)(h + (size_t)u0 * 128 + g * 8);
    for (int i = s; i < e; ++i) {
        int u1 = (i + 1 < e) ? csr_src[i + 1] : 0;
        if ((unsigned)u1 >= (unsigned)n) u1 = 0;
        float du1 = dinv[u1];
        short8 h1 = *(const short8*)(h + (size_t)u1 * 128 + g * 8);
        float w = di * du0;
#pragma unroll
        for (int j = 0; j < 8; ++j) acc[j] += bf2f((unsigned short)h0[j]) * w;
        u0 = u1; du0 = du1; h0 = h1;
    }

#pragma unroll
    for (int j = 0; j < 8; ++j)
        acc[j] = scrub(acc[j] + ldext(bias, g * 8 + j, xf));

    if (zf) {
        float* zp = (float*)z + (size_t)v * 128 + g * 8;
        f32x4 o0 = {acc[0], acc[1], acc[2], acc[3]};
        f32x4 o1 = {acc[4], acc[5], acc[6], acc[7]};
        *(f32x4*)zp = o0;
        *(f32x4*)(zp + 4) = o1;
    } else {
        short8 o;
#pragma unroll
        for (int j = 0; j < 8; ++j) o[j] = (short)f2bf(acc[j]);
        *(short8*)((unsigned short*)z + (size_t)v * 128 + g * 8) = o;
    }
}

// ---------------- launch ----------------

static inline size_t alignup(size_t x) { return (x + 255) & ~(size_t)255; }

extern "C" void kernel_launch(void* const* d_in, const int* in_sizes, int n_in,
                              void* d_out, int out_size, void* d_ws, size_t ws_size,
                              hipStream_t stream) {
    const void* x  = d_in[0];
    const int*  ei = (const int*)d_in[1];
    const void* W1 = d_in[2];
    const void* b1 = d_in[3];
    const void* W2 = d_in[4];
    const void* b2 = d_in[5];
    const void* Wp = d_in[6];
    const void* bp = d_in[7];

    const int HID = in_sizes[3];            // 128
    const int IN_DIM = in_sizes[2] / HID;   // 256
    const int N = in_sizes[0] / IN_DIM;     // 100000
    const int E = in_sizes[1] / 2;          // 1600000

    // workspace layout
    char* w = (char*)d_ws;
    int* flags = (int*)w;      w += 256;
    int* cnt = (int*)w;        w += alignup(sizeof(int) * (size_t)N);     // -> cursor
    int* rowptr = (int*)w;     w += alignup(sizeof(int) * (size_t)(N + 1));
    float* dinv = (float*)w;   w += alignup(sizeof(float) * (size_t)N);
    int* part = (int*)w;       w += 8192;                                  // scan partials
    int* csr_src = (int*)w;    w += alignup(sizeof(int) * (size_t)E);
    size_t fixed = (size_t)(w - (char*)d_ws);
    size_t bufbytes = alignup((size_t)N * HID * 2);
    bool wsmode = ws_size >= fixed + 2 * bufbytes;

    void* hC;  int h_half;
    void* z1p;
    if (wsmode) {
        hC = (void*)w;  h_half = 0;
        z1p = (void*)(w + bufbytes);
    } else {
        hC = d_out;     h_half = 1;
        z1p = d_out;
    }

    int nb256_N = (N + 255) / 256;
    int nb256_E = (E + 255) / 256;
    int nchunks = (N + CHUNK - 1) / CHUNK;
    int gemm_blocks = (N + 127) / 128;
    int agg_blocks = (N + 15) / 16;

    // probes + CSR build
    k_detect<<<1, 64, 0, stream>>>(ei, (const unsigned short*)x, flags);
    k_zero<<<nb256_N, 256, 0, stream>>>(cnt, N);
    k_count<<<nb256_E, 256, 0, stream>>>(ei, flags, cnt, E, N);
    k_part<<<nchunks, 256, 0, stream>>>(cnt, part, N);
    k_scanpart<<<1, 1024, 0, stream>>>(part, nchunks, rowptr, N, E);
    k_apply<<<nchunks, 256, 0, stream>>>(cnt, part, rowptr, dinv, N);
    k_scatter<<<nb256_E, 256, 0, stream>>>(ei, flags, cnt, csr_src, E, N);

    // layer 1: h1 = x@W1 (bf16 scratch); z1 = agg(h1)+b1 (bf16 scratch)
    k_gemm<<<gemm_blocks, 256, 0, stream>>>(x, W1, hC, nullptr, N, IN_DIM, flags,
                                            1, h_half, 0);
    k_agg<<<agg_blocks, 256, 0, stream>>>(hC, h_half, rowptr, csr_src, dinv, b1,
                                          z1p, 0, N, E, flags);

    // layer 2: h2 = z1@W2 (bf16 scratch); z2 = agg(h2)+b2 -> d_out half 0 (final fmt)
    k_gemm<<<gemm_blocks, 256, 0, stream>>>(z1p, W2, hC, nullptr, N, HID, flags,
                                            0, h_half, 0);
    k_agg<<<agg_blocks, 256, 0, stream>>>(hC, h_half, rowptr, csr_src, dinv, b2,
                                          d_out, 1, N, E, flags);

    // proj = z2@Wp + bp -> d_out half 1 (final fmt)
    k_gemm<<<gemm_blocks, 256, 0, stream>>>(d_out, Wp, d_out, bp, N, HID, flags,
                                            1, 1, 1);
}